// Round 1
// baseline (1600.776 us; speedup 1.0000x reference)
//
#include <hip/hip_runtime.h>
#include <math.h>

#define H      300
#define DW     300
#define DT     50
#define NLEAF  4096
#define BM     16
#define NTHR   640

__device__ __forceinline__ float sigmoidf_(float x) { return 1.0f / (1.0f + expf(-x)); }

// Precompute tag contributions (including biases):
//   tag_r[t][k] = br[k] + sum_j tag_table[t][j] * Wr[300+j][k]
//   tag_z[t][k] = bz[k] + sum_j tag_table[t][j] * Wz[300+j][k]
__global__ __launch_bounds__(320) void tag_kernel(
    const float* __restrict__ tag_table,
    const float* __restrict__ Wr, const float* __restrict__ br,
    const float* __restrict__ Wz, const float* __restrict__ bz,
    float* __restrict__ tag_r, float* __restrict__ tag_z)
{
    int t = blockIdx.x;
    int k = threadIdx.x;
    __shared__ float te[DT];
    if (k < DT) te[k] = tag_table[t * DT + k];
    __syncthreads();
    if (k < H) {
        float ar = br[k], az = bz[k];
        #pragma unroll 10
        for (int j = 0; j < DT; ++j) {
            float tv = te[j];
            ar = fmaf(tv, Wr[(DW + j) * H + k], ar);
            az = fmaf(tv, Wz[(DW + j) * H + k], az);
        }
        tag_r[t * H + k] = ar;
        tag_z[t * H + k] = az;
    }
}

// Leaf level: lh = rh = 0  =>  r unused, h = (1 - z) * u
//   z = sigmoid(we @ Wz[0:300] + tag_z[tag])
//   u = tanh  (we @ Wu[0:300] + bu)
__global__ __launch_bounds__(NTHR) void leaf_kernel(
    const int* __restrict__ word_ids, const int* __restrict__ tag_ids,
    const float* __restrict__ word_table,
    const float* __restrict__ Wz, const float* __restrict__ Wu,
    const float* __restrict__ bu, const float* __restrict__ tag_z,
    float* __restrict__ out)
{
    __shared__ float X[BM][DW + 4];   // gathered word embeddings
    __shared__ float Zs[BM][H + 4];   // z values
    int node0 = blockIdx.x * BM;
    int tid = threadIdx.x;

    for (int idx = tid; idx < BM * DW; idx += NTHR) {
        int j = idx / DW, d = idx - j * DW;
        X[j][d] = word_table[(long)word_ids[node0 + j] * DW + d];
    }
    __syncthreads();

    int k = (tid < H) ? tid : tid - H;
    bool isZ = (tid < H);
    float acc[BM];
    if (tid < 2 * H) {
        #pragma unroll
        for (int j = 0; j < BM; ++j) acc[j] = 0.f;
        const float* __restrict__ W = isZ ? Wz : Wu;
        for (int d = 0; d < DW; d += 4) {
            float w0 = W[(d + 0) * H + k];
            float w1 = W[(d + 1) * H + k];
            float w2 = W[(d + 2) * H + k];
            float w3 = W[(d + 3) * H + k];
            #pragma unroll
            for (int j = 0; j < BM; ++j) {
                float4 xv = *(const float4*)&X[j][d];
                acc[j] = fmaf(xv.x, w0, acc[j]);
                acc[j] = fmaf(xv.y, w1, acc[j]);
                acc[j] = fmaf(xv.z, w2, acc[j]);
                acc[j] = fmaf(xv.w, w3, acc[j]);
            }
        }
    }
    if (isZ) {
        #pragma unroll
        for (int j = 0; j < BM; ++j)
            Zs[j][k] = sigmoidf_(acc[j] + tag_z[tag_ids[node0 + j] * H + k]);
    }
    __syncthreads();
    if (!isZ && tid < 2 * H) {
        float b = bu[k];
        #pragma unroll
        for (int j = 0; j < BM; ++j) {
            float u = tanhf(acc[j] + b);
            out[(long)(node0 + j) * H + k] = (1.f - Zs[j][k]) * u;
        }
    }
}

// Internal level: we = 0.
// Phase A: r = sigmoid([lh|rh] @ Wr[350:950] + tag_r), z likewise with Wz.
// Phase B: u = tanh([r*lh | r*rh] @ Wu[300:900] + bu); h = z*(lh+rh) + (1-z)*u.
__global__ __launch_bounds__(NTHR) void level_kernel(
    const int* __restrict__ tag_ids,
    const float* __restrict__ Wr, const float* __restrict__ Wz,
    const float* __restrict__ Wu, const float* __restrict__ bu,
    const float* __restrict__ tag_r, const float* __restrict__ tag_z,
    float* __restrict__ out, int off, int prevOff, int m)
{
    __shared__ float X[BM][2 * H + 8];  // [lh|rh], later scaled in place by r
    __shared__ float Ss[BM][H + 4];     // lh + rh
    __shared__ float Zs[BM][H + 4];     // z
    int node0 = blockIdx.x * BM;
    int mloc = m - node0; if (mloc > BM) mloc = BM;
    int tid = threadIdx.x;

    for (int idx = tid; idx < mloc * 2 * H; idx += NTHR) {
        int j = idx / (2 * H), d = idx - j * (2 * H);
        int child = prevOff + 2 * (node0 + j) + (d >= H);
        X[j][d] = out[(long)child * H + (d < H ? d : d - H)];
    }
    __syncthreads();

    int k = (tid < H) ? tid : tid - H;
    bool isR = (tid < H);
    float acc[BM];
    if (tid < 2 * H) {
        #pragma unroll
        for (int j = 0; j < BM; ++j) acc[j] = 0.f;
        const float* __restrict__ W = (isR ? Wr : Wz) + 350 * H;
        for (int d = 0; d < 2 * H; d += 4) {
            float w0 = W[(d + 0) * H + k];
            float w1 = W[(d + 1) * H + k];
            float w2 = W[(d + 2) * H + k];
            float w3 = W[(d + 3) * H + k];
            #pragma unroll
            for (int j = 0; j < BM; ++j) {
                float4 xv = *(const float4*)&X[j][d];
                acc[j] = fmaf(xv.x, w0, acc[j]);
                acc[j] = fmaf(xv.y, w1, acc[j]);
                acc[j] = fmaf(xv.z, w2, acc[j]);
                acc[j] = fmaf(xv.w, w3, acc[j]);
            }
        }
    }
    __syncthreads();   // all phase-A reads of X complete before in-place scale

    if (tid < 2 * H) {
        if (isR) {
            for (int j = 0; j < mloc; ++j) {
                float r = sigmoidf_(acc[j] + tag_r[tag_ids[off + node0 + j] * H + k]);
                float lh = X[j][k], rh = X[j][H + k];
                Ss[j][k] = lh + rh;
                X[j][k]     = r * lh;
                X[j][H + k] = r * rh;
            }
        } else {
            for (int j = 0; j < mloc; ++j)
                Zs[j][k] = sigmoidf_(acc[j] + tag_z[tag_ids[off + node0 + j] * H + k]);
        }
    }
    __syncthreads();

    // Phase B: 600 threads, each handles one u column for 8 nodes.
    float accu[BM / 2];
    int jb = isR ? 0 : BM / 2;
    if (tid < 2 * H) {
        #pragma unroll
        for (int jj = 0; jj < BM / 2; ++jj) accu[jj] = 0.f;
        const float* __restrict__ W = Wu + 300 * H;
        for (int d = 0; d < 2 * H; d += 4) {
            float w0 = W[(d + 0) * H + k];
            float w1 = W[(d + 1) * H + k];
            float w2 = W[(d + 2) * H + k];
            float w3 = W[(d + 3) * H + k];
            #pragma unroll
            for (int jj = 0; jj < BM / 2; ++jj) {
                float4 xv = *(const float4*)&X[jb + jj][d];
                accu[jj] = fmaf(xv.x, w0, accu[jj]);
                accu[jj] = fmaf(xv.y, w1, accu[jj]);
                accu[jj] = fmaf(xv.z, w2, accu[jj]);
                accu[jj] = fmaf(xv.w, w3, accu[jj]);
            }
        }
        float b = bu[k];
        #pragma unroll
        for (int jj = 0; jj < BM / 2; ++jj) {
            int j = jb + jj;
            if (j < mloc) {
                float u = tanhf(accu[jj] + b);
                float z = Zs[j][k];
                out[(long)(off + node0 + j) * H + k] = z * Ss[j][k] + (1.f - z) * u;
            }
        }
    }
}

__global__ void copy_final(const float* __restrict__ src, float* __restrict__ dst)
{
    int k = threadIdx.x;
    if (k < H) dst[k] = src[k];
}

extern "C" void kernel_launch(void* const* d_in, const int* in_sizes, int n_in,
                              void* d_out, int out_size, void* d_ws, size_t ws_size,
                              hipStream_t stream)
{
    const int*   word_ids   = (const int*)  d_in[0];
    const int*   tag_ids    = (const int*)  d_in[1];
    const float* word_table = (const float*)d_in[2];
    const float* tag_table  = (const float*)d_in[3];
    const float* Wr         = (const float*)d_in[4];
    const float* br         = (const float*)d_in[5];
    const float* Wz         = (const float*)d_in[6];
    const float* bz         = (const float*)d_in[7];
    const float* Wu         = (const float*)d_in[8];
    const float* bu         = (const float*)d_in[9];
    float* out = (float*)d_out;

    float* tag_r = (float*)d_ws;            // 60*300 f32
    float* tag_z = tag_r + 60 * H;          // 60*300 f32

    tag_kernel<<<60, 320, 0, stream>>>(tag_table, Wr, br, Wz, bz, tag_r, tag_z);

    leaf_kernel<<<NLEAF / BM, NTHR, 0, stream>>>(
        word_ids, tag_ids, word_table, Wz, Wu, bu, tag_z, out);

    int off = NLEAF, prevOff = 0, m = NLEAF / 2;
    while (m >= 1) {
        int grid = (m + BM - 1) / BM;
        level_kernel<<<grid, NTHR, 0, stream>>>(
            tag_ids, Wr, Wz, Wu, bu, tag_r, tag_z, out, off, prevOff, m);
        prevOff = off;
        off += m;
        m >>= 1;
    }

    // final_state = last level's h (row 8190) appended after the 8191 output rows
    copy_final<<<1, 320, 0, stream>>>(out + (long)8190 * H, out + (long)8191 * H);
}

// Round 3
// 610.690 us; speedup vs baseline: 2.6213x; 2.6213x over previous
//
#include <hip/hip_runtime.h>
#include <math.h>

#define H      300
#define NLEAF  4096
#define NTHR   320

__device__ __forceinline__ float sigmoidf_(float x) { return 1.0f / (1.0f + expf(-x)); }

// tag_r[t][k] = br[k] + sum_j tag_table[t][j] * Wr[300+j][k]   (likewise tag_z)
__global__ __launch_bounds__(320) void tag_kernel(
    const float* __restrict__ tag_table,
    const float* __restrict__ Wr, const float* __restrict__ br,
    const float* __restrict__ Wz, const float* __restrict__ bz,
    float* __restrict__ tag_r, float* __restrict__ tag_z)
{
    int t = blockIdx.x;
    int k = threadIdx.x;
    __shared__ float te[50];
    if (k < 50) te[k] = tag_table[t * 50 + k];
    __syncthreads();
    if (k < H) {
        float ar = br[k], az = bz[k];
        #pragma unroll 10
        for (int j = 0; j < 50; ++j) {
            float tv = te[j];
            ar = fmaf(tv, Wr[(H + j) * H + k], ar);
            az = fmaf(tv, Wz[(H + j) * H + k], az);
        }
        tag_r[t * H + k] = ar;
        tag_z[t * H + k] = az;
    }
}

// Leaf: lh=rh=0 => r unused; h = (1-z)*u
//   z = sigmoid(we @ Wz[0:300] + tag_z[tag]);  u = tanh(we @ Wu[0:300] + bu)
// K-loop runs to 304 (38*8): X pad [300..303] is explicitly ZEROED so the
// extra weight rows (valid memory in both Wz/Wu) contribute exactly 0.
template<int NB>
__global__ __launch_bounds__(NTHR) void leaf_k(
    const int* __restrict__ word_ids, const int* __restrict__ tag_ids,
    const float* __restrict__ word_table,
    const float* __restrict__ Wz, const float* __restrict__ Wu,
    const float* __restrict__ bu, const float* __restrict__ tag_z,
    float* __restrict__ out)
{
    __shared__ float X[NB][H + 4];    // 304 floats; [300..303] zeroed
    __shared__ float Zs[NB][H + 4];
    int node0 = blockIdx.x * NB;
    int tid = threadIdx.x;

    for (int idx = tid; idx < NB * (H / 4); idx += NTHR) {
        int j = idx / (H / 4), q = idx - j * (H / 4);
        *(float4*)&X[j][q * 4] =
            *(const float4*)&word_table[(long)word_ids[node0 + j] * H + q * 4];
    }
    if (tid < NB) *(float4*)&X[tid][H] = make_float4(0.f, 0.f, 0.f, 0.f);
    __syncthreads();

    int t = tid;
    int isu = (t >= 150);
    int c0 = 2 * (t - 150 * isu);
    float acc[2][NB];
    if (t < 300) {
        #pragma unroll
        for (int c = 0; c < 2; ++c)
            #pragma unroll
            for (int j = 0; j < NB; ++j) acc[c][j] = 0.f;
        const float* __restrict__ W = (isu ? Wu : Wz) + c0;
        for (int d = 0; d < H + 4; d += 8) {      // 304 = 38*8; pad contributes 0
            float2 w[8];
            #pragma unroll
            for (int i = 0; i < 8; ++i) w[i] = *(const float2*)&W[(d + i) * H];
            #pragma unroll
            for (int j = 0; j < NB; ++j) {
                float xv[8];
                *(float4*)&xv[0] = *(const float4*)&X[j][d];
                *(float4*)&xv[4] = *(const float4*)&X[j][d + 4];
                #pragma unroll
                for (int i = 0; i < 8; ++i) {
                    acc[0][j] = fmaf(xv[i], w[i].x, acc[0][j]);
                    acc[1][j] = fmaf(xv[i], w[i].y, acc[1][j]);
                }
            }
        }
        if (!isu) {
            #pragma unroll
            for (int j = 0; j < NB; ++j) {
                int tg = tag_ids[node0 + j];
                Zs[j][c0]     = sigmoidf_(acc[0][j] + tag_z[tg * H + c0]);
                Zs[j][c0 + 1] = sigmoidf_(acc[1][j] + tag_z[tg * H + c0 + 1]);
            }
        }
    }
    __syncthreads();
    if (t >= 150 && t < 300) {
        float b0 = bu[c0], b1 = bu[c0 + 1];
        #pragma unroll
        for (int j = 0; j < NB; ++j) {
            float u0 = tanhf(acc[0][j] + b0);
            float u1 = tanhf(acc[1][j] + b1);
            float h0 = (1.f - Zs[j][c0]) * u0;
            float h1 = (1.f - Zs[j][c0 + 1]) * u1;
            *(float2*)&out[(long)(node0 + j) * H + c0] = make_float2(h0, h1);
        }
    }
}

// Internal level: we=0.  (K = 600, divisible by 8 — no pad needed.)
// A: pre_r = [lh|rh]@Wr[350:950]+tag_r ; pre_z likewise (Wz). r,z=sigmoid.
// B: u = tanh([r*lh|r*rh]@Wu[300:900]+bu); h = z*(lh+rh)+(1-z)*u
template<int NB>
__global__ __launch_bounds__(NTHR) void level_k(
    const int* __restrict__ tag_ids,
    const float* __restrict__ Wr, const float* __restrict__ Wz,
    const float* __restrict__ Wu, const float* __restrict__ bu,
    const float* __restrict__ tag_r, const float* __restrict__ tag_z,
    float* __restrict__ out, int off, int prevOff)
{
    __shared__ float X[NB][2 * H + 8];   // [lh|rh], scaled by r in place
    __shared__ float Ss[NB][H + 4];      // lh+rh
    __shared__ float Zs[NB][H + 4];      // z
    int node0 = blockIdx.x * NB;
    int tid = threadIdx.x;

    for (int idx = tid; idx < NB * 150; idx += NTHR) {
        int j = idx / 150, q = idx - j * 150;
        int half = q / 75, qq = q - half * 75;
        *(float4*)&X[j][half * H + qq * 4] =
            *(const float4*)&out[(long)(prevOff + 2 * (node0 + j) + half) * H + qq * 4];
    }
    __syncthreads();

    int t = tid;
    int isz = (t >= 150);
    int c0 = 2 * (t - 150 * isz);
    float accA[2][NB];
    if (t < 300) {
        #pragma unroll
        for (int c = 0; c < 2; ++c)
            #pragma unroll
            for (int j = 0; j < NB; ++j) accA[c][j] = 0.f;
        const float* __restrict__ WA = (isz ? Wz : Wr) + 350 * H + c0;
        for (int d = 0; d < 2 * H; d += 8) {
            float2 w[8];
            #pragma unroll
            for (int i = 0; i < 8; ++i) w[i] = *(const float2*)&WA[(d + i) * H];
            #pragma unroll
            for (int j = 0; j < NB; ++j) {
                float xv[8];
                *(float4*)&xv[0] = *(const float4*)&X[j][d];
                *(float4*)&xv[4] = *(const float4*)&X[j][d + 4];
                #pragma unroll
                for (int i = 0; i < 8; ++i) {
                    accA[0][j] = fmaf(xv[i], w[i].x, accA[0][j]);
                    accA[1][j] = fmaf(xv[i], w[i].y, accA[1][j]);
                }
            }
        }
    }
    __syncthreads();   // all GEMM reads of X complete before in-place scale

    if (t < 300) {
        if (!isz) {
            #pragma unroll
            for (int j = 0; j < NB; ++j) {
                int tg = tag_ids[off + node0 + j];
                float r0 = sigmoidf_(accA[0][j] + tag_r[tg * H + c0]);
                float r1 = sigmoidf_(accA[1][j] + tag_r[tg * H + c0 + 1]);
                float l0 = X[j][c0], l1 = X[j][c0 + 1];
                float q0 = X[j][H + c0], q1 = X[j][H + c0 + 1];
                Ss[j][c0]     = l0 + q0;
                Ss[j][c0 + 1] = l1 + q1;
                X[j][c0]     = r0 * l0;  X[j][c0 + 1] = r1 * l1;
                X[j][H + c0] = r0 * q0;  X[j][H + c0 + 1] = r1 * q1;
            }
        } else {
            #pragma unroll
            for (int j = 0; j < NB; ++j) {
                int tg = tag_ids[off + node0 + j];
                Zs[j][c0]     = sigmoidf_(accA[0][j] + tag_z[tg * H + c0]);
                Zs[j][c0 + 1] = sigmoidf_(accA[1][j] + tag_z[tg * H + c0 + 1]);
            }
        }
    }
    __syncthreads();

    // Phase B: split nodes between the two 150-thread groups (if NB>1)
    constexpr int NBB = (NB > 1) ? NB / 2 : 1;
    int jb = (NB > 1) ? isz * NBB : 0;
    bool actB = (t < 300) && (NB > 1 || !isz);
    if (actB) {
        float accB[2][NBB];
        #pragma unroll
        for (int c = 0; c < 2; ++c)
            #pragma unroll
            for (int jj = 0; jj < NBB; ++jj) accB[c][jj] = 0.f;
        const float* __restrict__ WB = Wu + 300 * H + c0;
        for (int d = 0; d < 2 * H; d += 8) {
            float2 w[8];
            #pragma unroll
            for (int i = 0; i < 8; ++i) w[i] = *(const float2*)&WB[(d + i) * H];
            #pragma unroll
            for (int jj = 0; jj < NBB; ++jj) {
                float xv[8];
                *(float4*)&xv[0] = *(const float4*)&X[jb + jj][d];
                *(float4*)&xv[4] = *(const float4*)&X[jb + jj][d + 4];
                #pragma unroll
                for (int i = 0; i < 8; ++i) {
                    accB[0][jj] = fmaf(xv[i], w[i].x, accB[0][jj]);
                    accB[1][jj] = fmaf(xv[i], w[i].y, accB[1][jj]);
                }
            }
        }
        float b0 = bu[c0], b1 = bu[c0 + 1];
        #pragma unroll
        for (int jj = 0; jj < NBB; ++jj) {
            int j = jb + jj;
            float u0 = tanhf(accB[0][jj] + b0);
            float u1 = tanhf(accB[1][jj] + b1);
            float z0 = Zs[j][c0], z1 = Zs[j][c0 + 1];
            float h0 = z0 * Ss[j][c0]     + (1.f - z0) * u0;
            float h1 = z1 * Ss[j][c0 + 1] + (1.f - z1) * u1;
            *(float2*)&out[(long)(off + node0 + j) * H + c0] = make_float2(h0, h1);
        }
    }
}

__global__ void copy_final(const float* __restrict__ src, float* __restrict__ dst)
{
    int k = threadIdx.x;
    if (k < H) dst[k] = src[k];
}

extern "C" void kernel_launch(void* const* d_in, const int* in_sizes, int n_in,
                              void* d_out, int out_size, void* d_ws, size_t ws_size,
                              hipStream_t stream)
{
    const int*   word_ids   = (const int*)  d_in[0];
    const int*   tag_ids    = (const int*)  d_in[1];
    const float* word_table = (const float*)d_in[2];
    const float* tag_table  = (const float*)d_in[3];
    const float* Wr         = (const float*)d_in[4];
    const float* br         = (const float*)d_in[5];
    const float* Wz         = (const float*)d_in[6];
    const float* bz         = (const float*)d_in[7];
    const float* Wu         = (const float*)d_in[8];
    const float* bu         = (const float*)d_in[9];
    float* out = (float*)d_out;

    float* tag_r = (float*)d_ws;
    float* tag_z = tag_r + 60 * H;

    tag_kernel<<<60, 320, 0, stream>>>(tag_table, Wr, br, Wz, bz, tag_r, tag_z);

    leaf_k<16><<<NLEAF / 16, NTHR, 0, stream>>>(
        word_ids, tag_ids, word_table, Wz, Wu, bu, tag_z, out);

    int off = NLEAF, prevOff = 0, m = NLEAF / 2;
    while (m >= 1) {
        if (m >= 1024)
            level_k<8><<<m / 8, NTHR, 0, stream>>>(tag_ids, Wr, Wz, Wu, bu, tag_r, tag_z, out, off, prevOff);
        else if (m >= 256)
            level_k<4><<<m / 4, NTHR, 0, stream>>>(tag_ids, Wr, Wz, Wu, bu, tag_r, tag_z, out, off, prevOff);
        else if (m == 128)
            level_k<2><<<m / 2, NTHR, 0, stream>>>(tag_ids, Wr, Wz, Wu, bu, tag_r, tag_z, out, off, prevOff);
        else
            level_k<1><<<m, NTHR, 0, stream>>>(tag_ids, Wr, Wz, Wu, bu, tag_r, tag_z, out, off, prevOff);
        prevOff = off;
        off += m;
        m >>= 1;
    }

    copy_final<<<1, 320, 0, stream>>>(out + (long)8190 * H, out + (long)8191 * H);
}

// Round 4
// 576.278 us; speedup vs baseline: 2.7778x; 1.0597x over previous
//
#include <hip/hip_runtime.h>
#include <math.h>

#define H      300
#define NLEAF  4096
#define NTHR   320

__device__ __forceinline__ float sigmoidf_(float x) { return 1.0f / (1.0f + expf(-x)); }

// Load next 8 weight rows (2 cols) and advance pointer
#define LDW(buf) { _Pragma("unroll") \
    for (int i = 0; i < 8; ++i) buf[i] = *(const float2*)&wp[i * H]; \
    wp += 8 * H; }

// 8 k-steps * 2 cols FMA for NN nodes starting at row jbase of X
#define FMA8X(buf, dd, jbase, NN, a0, a1) { _Pragma("unroll") \
    for (int j = 0; j < NN; ++j) { \
        float4 xlo = *(const float4*)&X[(jbase) + j][(dd)]; \
        float4 xhi = *(const float4*)&X[(jbase) + j][(dd) + 4]; \
        a0[j] = fmaf(xlo.x, buf[0].x, a0[j]); a1[j] = fmaf(xlo.x, buf[0].y, a1[j]); \
        a0[j] = fmaf(xlo.y, buf[1].x, a0[j]); a1[j] = fmaf(xlo.y, buf[1].y, a1[j]); \
        a0[j] = fmaf(xlo.z, buf[2].x, a0[j]); a1[j] = fmaf(xlo.z, buf[2].y, a1[j]); \
        a0[j] = fmaf(xlo.w, buf[3].x, a0[j]); a1[j] = fmaf(xlo.w, buf[3].y, a1[j]); \
        a0[j] = fmaf(xhi.x, buf[4].x, a0[j]); a1[j] = fmaf(xhi.x, buf[4].y, a1[j]); \
        a0[j] = fmaf(xhi.y, buf[5].x, a0[j]); a1[j] = fmaf(xhi.y, buf[5].y, a1[j]); \
        a0[j] = fmaf(xhi.z, buf[6].x, a0[j]); a1[j] = fmaf(xhi.z, buf[6].y, a1[j]); \
        a0[j] = fmaf(xhi.w, buf[7].x, a0[j]); a1[j] = fmaf(xhi.w, buf[7].y, a1[j]); } }

// tag_r[t][k] = br[k] + sum_j tag_table[t][j] * Wr[300+j][k]   (likewise tag_z)
__global__ __launch_bounds__(320) void tag_kernel(
    const float* __restrict__ tag_table,
    const float* __restrict__ Wr, const float* __restrict__ br,
    const float* __restrict__ Wz, const float* __restrict__ bz,
    float* __restrict__ tag_r, float* __restrict__ tag_z)
{
    int t = blockIdx.x;
    int k = threadIdx.x;
    __shared__ float te[50];
    if (k < 50) te[k] = tag_table[t * 50 + k];
    __syncthreads();
    if (k < H) {
        float ar = br[k], az = bz[k];
        #pragma unroll 10
        for (int j = 0; j < 50; ++j) {
            float tv = te[j];
            ar = fmaf(tv, Wr[(H + j) * H + k], ar);
            az = fmaf(tv, Wz[(H + j) * H + k], az);
        }
        tag_r[t * H + k] = ar;
        tag_z[t * H + k] = az;
    }
}

// Leaf: lh=rh=0 => r unused; h = (1-z)*u
// K padded 300->304 (38 chunks of 8); X[.][300..303]=0, extra weight rows
// (valid memory in Wz[950x300]/Wu[900x300]) multiply exact zeros.
template<int NB>
__global__ __launch_bounds__(NTHR) void leaf_k(
    const int* __restrict__ word_ids, const int* __restrict__ tag_ids,
    const float* __restrict__ word_table,
    const float* __restrict__ Wz, const float* __restrict__ Wu,
    const float* __restrict__ bu, const float* __restrict__ tag_z,
    float* __restrict__ out)
{
    __shared__ float X[NB][H + 4];
    __shared__ float Zs[NB][H + 4];
    int node0 = blockIdx.x * NB;
    int tid = threadIdx.x;

    for (int idx = tid; idx < NB * 75; idx += NTHR) {
        int j = idx / 75, q = idx - j * 75;
        *(float4*)&X[j][q * 4] =
            *(const float4*)&word_table[(long)word_ids[node0 + j] * H + q * 4];
    }
    if (tid < NB) *(float4*)&X[tid][H] = make_float4(0.f, 0.f, 0.f, 0.f);
    __syncthreads();

    int t = tid;
    int isu = (t >= 150);
    int c0 = 2 * (t - 150 * isu);
    float acc0[NB], acc1[NB];
    if (t < 300) {
        #pragma unroll
        for (int j = 0; j < NB; ++j) { acc0[j] = 0.f; acc1[j] = 0.f; }
        const float* wp = (isu ? Wu : Wz) + c0;
        float2 wa[8], wb[8];
        LDW(wa);                       // chunk 0
        int d = 0;
        for (int ch = 0; ch + 1 < 38; ch += 2) {
            LDW(wb);                   // chunk ch+1
            FMA8X(wa, d, 0, NB, acc0, acc1);
            if (ch + 2 < 38) LDW(wa);  // chunk ch+2
            FMA8X(wb, d + 8, 0, NB, acc0, acc1);
            d += 16;
        }
        if (!isu) {
            #pragma unroll
            for (int j = 0; j < NB; ++j) {
                int tg = tag_ids[node0 + j];
                Zs[j][c0]     = sigmoidf_(acc0[j] + tag_z[tg * H + c0]);
                Zs[j][c0 + 1] = sigmoidf_(acc1[j] + tag_z[tg * H + c0 + 1]);
            }
        }
    }
    __syncthreads();
    if (t >= 150 && t < 300) {
        float b0 = bu[c0], b1 = bu[c0 + 1];
        #pragma unroll
        for (int j = 0; j < NB; ++j) {
            float u0 = tanhf(acc0[j] + b0);
            float u1 = tanhf(acc1[j] + b1);
            float h0 = (1.f - Zs[j][c0]) * u0;
            float h1 = (1.f - Zs[j][c0 + 1]) * u1;
            *(float2*)&out[(long)(node0 + j) * H + c0] = make_float2(h0, h1);
        }
    }
}

// Internal level: we=0. K=600 (75 chunks of 8).
// A: pre_r = [lh|rh]@Wr[350:950]+tag_r ; pre_z likewise (Wz). r,z=sigmoid.
// B: u = tanh([r*lh|r*rh]@Wu[300:900]+bu); h = z*(lh+rh)+(1-z)*u
template<int NB>
__global__ __launch_bounds__(NTHR) void level_k(
    const int* __restrict__ tag_ids,
    const float* __restrict__ Wr, const float* __restrict__ Wz,
    const float* __restrict__ Wu, const float* __restrict__ bu,
    const float* __restrict__ tag_r, const float* __restrict__ tag_z,
    float* __restrict__ out, int off, int prevOff)
{
    __shared__ float X[NB][2 * H + 8];   // [lh|rh], scaled by r in place
    __shared__ float Ss[NB][H + 4];      // lh+rh
    __shared__ float Zs[NB][H + 4];      // z
    int node0 = blockIdx.x * NB;
    int tid = threadIdx.x;

    for (int idx = tid; idx < NB * 150; idx += NTHR) {
        int j = idx / 150, q = idx - j * 150;
        int half = q / 75, qq = q - half * 75;
        *(float4*)&X[j][half * H + qq * 4] =
            *(const float4*)&out[(long)(prevOff + 2 * (node0 + j) + half) * H + qq * 4];
    }
    __syncthreads();

    int t = tid;
    int isz = (t >= 150);
    int c0 = 2 * (t - 150 * isz);
    float acc0[NB], acc1[NB];
    if (t < 300) {
        #pragma unroll
        for (int j = 0; j < NB; ++j) { acc0[j] = 0.f; acc1[j] = 0.f; }
        const float* wp = ((isz ? Wz : Wr) + 350 * H) + c0;
        float2 wa[8], wb[8];
        LDW(wa);
        int d = 0;
        for (int ch = 0; ch + 1 < 75; ch += 2) {
            LDW(wb);
            FMA8X(wa, d, 0, NB, acc0, acc1);
            if (ch + 2 < 75) LDW(wa);
            FMA8X(wb, d + 8, 0, NB, acc0, acc1);
            d += 16;
        }
        FMA8X(wa, 74 * 8, 0, NB, acc0, acc1);   // odd chunk count
    }
    __syncthreads();   // all GEMM reads of X complete before in-place scale

    if (t < 300) {
        if (!isz) {
            #pragma unroll
            for (int j = 0; j < NB; ++j) {
                int tg = tag_ids[off + node0 + j];
                float r0 = sigmoidf_(acc0[j] + tag_r[tg * H + c0]);
                float r1 = sigmoidf_(acc1[j] + tag_r[tg * H + c0 + 1]);
                float l0 = X[j][c0], l1 = X[j][c0 + 1];
                float q0 = X[j][H + c0], q1 = X[j][H + c0 + 1];
                Ss[j][c0]     = l0 + q0;
                Ss[j][c0 + 1] = l1 + q1;
                X[j][c0]     = r0 * l0;  X[j][c0 + 1] = r1 * l1;
                X[j][H + c0] = r0 * q0;  X[j][H + c0 + 1] = r1 * q1;
            }
        } else {
            #pragma unroll
            for (int j = 0; j < NB; ++j) {
                int tg = tag_ids[off + node0 + j];
                Zs[j][c0]     = sigmoidf_(acc0[j] + tag_z[tg * H + c0]);
                Zs[j][c0 + 1] = sigmoidf_(acc1[j] + tag_z[tg * H + c0 + 1]);
            }
        }
    }
    __syncthreads();

    // Phase B: split nodes between the two 150-thread groups (if NB>1)
    constexpr int NBB = (NB > 1) ? NB / 2 : 1;
    int jb = (NB > 1) ? isz * NBB : 0;
    bool actB = (t < 300) && (NB > 1 || !isz);
    if (actB) {
        float b0a[NBB], b1a[NBB];
        #pragma unroll
        for (int jj = 0; jj < NBB; ++jj) { b0a[jj] = 0.f; b1a[jj] = 0.f; }
        const float* wp = (Wu + 300 * H) + c0;
        float2 wa[8], wb[8];
        LDW(wa);
        int d = 0;
        for (int ch = 0; ch + 1 < 75; ch += 2) {
            LDW(wb);
            FMA8X(wa, d, jb, NBB, b0a, b1a);
            if (ch + 2 < 75) LDW(wa);
            FMA8X(wb, d + 8, jb, NBB, b0a, b1a);
            d += 16;
        }
        FMA8X(wa, 74 * 8, jb, NBB, b0a, b1a);
        float bb0 = bu[c0], bb1 = bu[c0 + 1];
        #pragma unroll
        for (int jj = 0; jj < NBB; ++jj) {
            int j = jb + jj;
            float u0 = tanhf(b0a[jj] + bb0);
            float u1 = tanhf(b1a[jj] + bb1);
            float z0 = Zs[j][c0], z1 = Zs[j][c0 + 1];
            float h0 = z0 * Ss[j][c0]     + (1.f - z0) * u0;
            float h1 = z1 * Ss[j][c0 + 1] + (1.f - z1) * u1;
            *(float2*)&out[(long)(off + node0 + j) * H + c0] = make_float2(h0, h1);
        }
    }
}

__global__ void copy_final(const float* __restrict__ src, float* __restrict__ dst)
{
    int k = threadIdx.x;
    if (k < H) dst[k] = src[k];
}

extern "C" void kernel_launch(void* const* d_in, const int* in_sizes, int n_in,
                              void* d_out, int out_size, void* d_ws, size_t ws_size,
                              hipStream_t stream)
{
    const int*   word_ids   = (const int*)  d_in[0];
    const int*   tag_ids    = (const int*)  d_in[1];
    const float* word_table = (const float*)d_in[2];
    const float* tag_table  = (const float*)d_in[3];
    const float* Wr         = (const float*)d_in[4];
    const float* br         = (const float*)d_in[5];
    const float* Wz         = (const float*)d_in[6];
    const float* bz         = (const float*)d_in[7];
    const float* Wu         = (const float*)d_in[8];
    const float* bu         = (const float*)d_in[9];
    float* out = (float*)d_out;

    float* tag_r = (float*)d_ws;
    float* tag_z = tag_r + 60 * H;

    tag_kernel<<<60, 320, 0, stream>>>(tag_table, Wr, br, Wz, bz, tag_r, tag_z);

    leaf_k<8><<<NLEAF / 8, NTHR, 0, stream>>>(
        word_ids, tag_ids, word_table, Wz, Wu, bu, tag_z, out);

    int off = NLEAF, prevOff = 0, m = NLEAF / 2;
    while (m >= 1) {
        if (m == 2048)
            level_k<8><<<256, NTHR, 0, stream>>>(tag_ids, Wr, Wz, Wu, bu, tag_r, tag_z, out, off, prevOff);
        else if (m == 1024)
            level_k<4><<<256, NTHR, 0, stream>>>(tag_ids, Wr, Wz, Wu, bu, tag_r, tag_z, out, off, prevOff);
        else if (m == 512)
            level_k<2><<<256, NTHR, 0, stream>>>(tag_ids, Wr, Wz, Wu, bu, tag_r, tag_z, out, off, prevOff);
        else
            level_k<1><<<m, NTHR, 0, stream>>>(tag_ids, Wr, Wz, Wu, bu, tag_r, tag_z, out, off, prevOff);
        prevOff = off;
        off += m;
        m >>= 1;
    }

    copy_final<<<1, 320, 0, stream>>>(out + (long)8190 * H, out + (long)8191 * H);
}